// Round 3
// baseline (359.733 us; speedup 1.0000x reference)
//
#include <hip/hip_runtime.h>

// Problem dims (hardcoded from reference)
#define T_STEPS 100
#define B_N     128
#define IN_F    512
#define OUT_F   512

// fp64 decay constants: exp(-DT/TAU_*)
#define ALPHA_D 0.8187307530779818   // exp(-1/5)   synaptic
#define BETA_D  0.9512294245007140   // exp(-1/20)  membrane

// ---------------------------------------------------------------------------
// K1: transpose W (OUT x IN) -> Wt (IN x OUT).
// ---------------------------------------------------------------------------
__global__ __launch_bounds__(256) void transposeW(const float* __restrict__ W,
                                                  float* __restrict__ Wt) {
    __shared__ float tile[32][33];
    const int bx = blockIdx.x & 15;   // i-tile
    const int by = blockIdx.x >> 4;   // o-tile
    const int tx = threadIdx.x & 31;
    const int ty = threadIdx.x >> 5;  // 0..7
#pragma unroll
    for (int k = 0; k < 32; k += 8) {
        int o = by * 32 + ty + k;
        tile[ty + k][tx] = W[o * IN_F + bx * 32 + tx];
    }
    __syncthreads();
#pragma unroll
    for (int k = 0; k < 32; k += 8) {
        int i = bx * 32 + ty + k;
        Wt[i * OUT_F + by * 32 + tx] = tile[tx][ty + k];
    }
}

// ---------------------------------------------------------------------------
// K_A: C[t,b,o] = sum over active i of Wt[i][o], fp64. One block per (t,b).
// ---------------------------------------------------------------------------
__global__ __launch_bounds__(256) void syn_current(const float* __restrict__ x,
                                                   const float* __restrict__ Wt,
                                                   double* __restrict__ C) {
    const int tb  = blockIdx.x;          // t*B + b
    const int tid = threadIdx.x;

    __shared__ int s_idx[IN_F];
    __shared__ int s_cnt;

    if (tid < 64) {                      // wave 0 builds ascending active list
        const float* xr = x + (size_t)tb * IN_F;
        int base = 0;
#pragma unroll
        for (int j = 0; j < 8; ++j) {
            const float v = xr[j * 64 + tid];
            const unsigned long long m = __ballot(v > 0.5f);
            if (v > 0.5f) {
                const int pos = base + __popcll(m & ((1ull << tid) - 1ull));
                s_idx[pos] = j * 64 + tid;
            }
            base += __popcll(m);
        }
        if (tid == 0) s_cnt = base;
    }
    __syncthreads();

    const int cnt = s_cnt;
    double c0 = 0.0, c1 = 0.0;
    const float* W0 = Wt + tid;
    const float* W1 = Wt + tid + 256;
    for (int k = 0; k < cnt; ++k) {
        const int i = s_idx[k];          // LDS broadcast (uniform address)
        c0 += (double)W0[(size_t)i * OUT_F];
        c1 += (double)W1[(size_t)i * OUT_F];
    }

    double* Cr = C + (size_t)tb * OUT_F;
    Cr[tid]       = c0;
    Cr[tid + 256] = c1;
}

// ---------------------------------------------------------------------------
// K_B: elementwise LIF scan, one thread per (b,o). fp64 recurrence,
// double-buffered 10-step chunks (static indices only).
// ---------------------------------------------------------------------------
#define LIF_STEP(BUF, J, CB)                                                   \
    {                                                                          \
        const int t = (CB) * 10 + (J);                                         \
        I = ALPHA_D * I + BUF[J];                                              \
        U = BETA_D * U + I;                                                    \
        const double Sv = (U >= 1.0) ? 1.0 : 0.0;                              \
        S_out[(size_t)t * N + pos] = (float)Sv;                                \
        Uh[(size_t)(2 * t) * N + pos] = (float)U;                              \
        U -= Sv;                                                               \
        Uh[(size_t)(2 * t + 1) * N + pos] = (float)U;                          \
        U -= Sv;                                                               \
    }

__global__ __launch_bounds__(256) void lif_pointwise(const double* __restrict__ C,
                                                     float* __restrict__ S_out,
                                                     float* __restrict__ Uh) {
    const int pos = blockIdx.x * 256 + threadIdx.x;   // b*OUT + o
    const size_t N = (size_t)B_N * OUT_F;

    double I = 0.0, U = 0.0;
    double bufA[10], bufB[10];

#pragma unroll
    for (int j = 0; j < 10; ++j) bufA[j] = C[(size_t)j * N + pos];

    for (int cb = 0; cb < 10; cb += 2) {
#pragma unroll
        for (int j = 0; j < 10; ++j) bufB[j] = C[((size_t)(cb + 1) * 10 + j) * N + pos];
#pragma unroll
        for (int j = 0; j < 10; ++j) LIF_STEP(bufA, j, cb)
        if (cb + 2 < 10) {
#pragma unroll
            for (int j = 0; j < 10; ++j) bufA[j] = C[((size_t)(cb + 2) * 10 + j) * N + pos];
        }
#pragma unroll
        for (int j = 0; j < 10; ++j) LIF_STEP(bufB, j, cb + 1)
    }
}

// ---------------------------------------------------------------------------
// K3': SPARSE trace. x is binary (~10% dense), so
//   trace[b,o,i] = sum_{t : x[t,b,i]=1} P[t,b,o],  P = sigma'(U_post)*gamma^(T-1-t)
// Per block (b, 64x64 o/i tile): wave 0 builds per-i active-t byte lists
// stored TRANSPOSED tl[k][i] (4 lists per dword); waves 1-3 stage P tile
// (padded stride 68 -> t mod 8 bank spread; row 100 = zero sentinel).
// Compute loop is branchless: sentinel-padded lists add Pl[100]=0.
// Per-thread: ~18 iters x {1 ds_read_b32, 4 ds_read_b128, 16 v_add} vs the
// dense 100 x {2 ds_read_b128, 16 v_fma} -> ~3.5x fewer VALU/LDS ops.
// ---------------------------------------------------------------------------
__global__ __launch_bounds__(256) void trace_sparse(const float* __restrict__ x,
                                                    const float* __restrict__ Uh,
                                                    float* __restrict__ trace) {
    __shared__ float Pl[T_STEPS + 1][68];   // 272B stride (16B-aligned), row 100 = 0
    __shared__ unsigned int tl4[104][16];   // byte view: tl[k][i], sentinel 100
    __shared__ int tcnt[64];

    const int b    = blockIdx.x & (B_N - 1);
    const int tile = blockIdx.x >> 7;     // 0..63
    const int ot   = tile >> 3;           // o-tile 0..7
    const int it   = tile & 7;            // i-tile 0..7
    const int tid  = threadIdx.x;

    // init lists to sentinel t=100 (0x64)
    for (int idx = tid; idx < 104 * 16; idx += 256)
        ((unsigned int*)tl4)[idx] = 0x64646464u;
    __syncthreads();

    if (tid < 64) {
        // wave 0: per-column active-t list for i = it*64 + tid
        unsigned char* tlb = (unsigned char*)tl4;
        int c = 0;
        const float* xc = x + (size_t)b * IN_F + it * 64 + tid;
#pragma unroll 4
        for (int t = 0; t < T_STEPS; ++t) {
            const float v = xc[(size_t)t * (B_N * IN_F)];
            if (v > 0.5f) { tlb[c * 64 + tid] = (unsigned char)t; ++c; }
        }
        tcnt[tid] = c;
    } else {
        // waves 1-3: stage P tile from U_post
        for (int idx = tid - 64; idx < T_STEPS * 64; idx += 192) {
            const int t = idx >> 6, col = idx & 63;
            const float u  = Uh[(size_t)(2 * t + 1) * (B_N * OUT_F) + (size_t)b * OUT_F + ot * 64 + col];
            const float du = fabsf(u - 1.0f);
            const float d  = 1.0f + 0.03f * du;
            const float gp = __expf(-0.05f * (float)(T_STEPS - 1 - t));  // gamma^(T-1-t)
            Pl[t][col] = gp / (d * d);
        }
        if (tid - 64 < 64) Pl[T_STEPS][tid - 64] = 0.0f;   // sentinel row
    }
    __syncthreads();

    const int to = tid >> 4;   // 0..15: o sub-row *4
    const int ti = tid & 15;   // 0..15: i sub-col *4
    const int i0 = ti * 4;

    const int n0 = tcnt[i0], n1 = tcnt[i0 + 1], n2 = tcnt[i0 + 2], n3 = tcnt[i0 + 3];
    int nm = n0 > n1 ? n0 : n1;
    nm = nm > n2 ? nm : n2;
    nm = nm > n3 ? nm : n3;

    float4 a0 = {0, 0, 0, 0}, a1 = {0, 0, 0, 0}, a2 = {0, 0, 0, 0}, a3 = {0, 0, 0, 0};
    const unsigned int* tcol = &tl4[0][ti];

    for (int k = 0; k < nm; ++k) {
        const unsigned int p = tcol[(size_t)k * 16];   // 4 t-indices, one dword
        const int t0 = p & 0xFF;
        const int t1 = (p >> 8) & 0xFF;
        const int t2 = (p >> 16) & 0xFF;
        const int t3 = p >> 24;
        const float4 p0 = *(const float4*)&Pl[t0][to * 4];
        const float4 p1 = *(const float4*)&Pl[t1][to * 4];
        const float4 p2 = *(const float4*)&Pl[t2][to * 4];
        const float4 p3 = *(const float4*)&Pl[t3][to * 4];
        a0.x += p0.x; a0.y += p0.y; a0.z += p0.z; a0.w += p0.w;
        a1.x += p1.x; a1.y += p1.y; a1.z += p1.z; a1.w += p1.w;
        a2.x += p2.x; a2.y += p2.y; a2.z += p2.z; a2.w += p2.w;
        a3.x += p3.x; a3.y += p3.y; a3.z += p3.z; a3.w += p3.w;
    }

    // a_q[r] = trace(o = ot*64+to*4+r, i = it*64+i0+q); transpose to row-major
    float* tb = trace + (size_t)b * (OUT_F * IN_F) + (size_t)(ot * 64 + to * 4) * IN_F + it * 64 + i0;
    const float4 r0 = {a0.x, a1.x, a2.x, a3.x};
    const float4 r1 = {a0.y, a1.y, a2.y, a3.y};
    const float4 r2 = {a0.z, a1.z, a2.z, a3.z};
    const float4 r3 = {a0.w, a1.w, a2.w, a3.w};
    *(float4*)(tb + 0 * IN_F) = r0;
    *(float4*)(tb + 1 * IN_F) = r1;
    *(float4*)(tb + 2 * IN_F) = r2;
    *(float4*)(tb + 3 * IN_F) = r3;
}

// ---------------------------------------------------------------------------
extern "C" void kernel_launch(void* const* d_in, const int* in_sizes, int n_in,
                              void* d_out, int out_size, void* d_ws, size_t ws_size,
                              hipStream_t stream) {
    const float* x = (const float*)d_in[0];   // (T, B, IN) binary spikes
    const float* W = (const float*)d_in[1];   // (OUT, IN)

    float* out   = (float*)d_out;
    float* S_out = out;                                            // (T, B, OUT)
    float* Uh    = out + (size_t)T_STEPS * B_N * OUT_F;            // (2T, B, OUT)
    float* trace = Uh + (size_t)2 * T_STEPS * B_N * OUT_F;         // (B, OUT, IN)

    float* Wt = (float*)d_ws;                                      // (IN, OUT), 1 MiB

    // Scratch for C: reuse the trace region of d_out (134 MB >= 52 MB needed);
    // trace_sparse runs last and overwrites it.
    double* C = (double*)trace;

    transposeW<<<256, 256, 0, stream>>>(W, Wt);
    syn_current<<<T_STEPS * B_N, 256, 0, stream>>>(x, Wt, C);
    lif_pointwise<<<B_N * OUT_F / 256, 256, 0, stream>>>(C, S_out, Uh);
    trace_sparse<<<64 * B_N, 256, 0, stream>>>(x, Uh, trace);
}

// Round 4
// 158.075 us; speedup vs baseline: 2.2757x; 2.2757x over previous
//
#include <hip/hip_runtime.h>

// Problem dims (hardcoded from reference)
#define T_STEPS 100
#define B_N     128
#define IN_F    512
#define OUT_F   512

// fp64 decay constants: exp(-DT/TAU_*)
#define ALPHA_D 0.8187307530779818   // exp(-1/5)   synaptic
#define BETA_D  0.9512294245007140   // exp(-1/20)  membrane

typedef __attribute__((ext_vector_type(8))) short bf16x8;
typedef __attribute__((ext_vector_type(4))) float f32x4;

static __device__ __forceinline__ unsigned short f2bf(float f) {
    union { float f; unsigned int u; } v; v.f = f;
    unsigned int r = (v.u + 0x7FFFu + ((v.u >> 16) & 1u)) >> 16;   // RNE
    return (unsigned short)r;
}

// ---------------------------------------------------------------------------
// K1: transpose W (OUT x IN) -> Wt (IN x OUT).
// ---------------------------------------------------------------------------
__global__ __launch_bounds__(256) void transposeW(const float* __restrict__ W,
                                                  float* __restrict__ Wt) {
    __shared__ float tile[32][33];
    const int bx = blockIdx.x & 15;   // i-tile
    const int by = blockIdx.x >> 4;   // o-tile
    const int tx = threadIdx.x & 31;
    const int ty = threadIdx.x >> 5;  // 0..7
#pragma unroll
    for (int k = 0; k < 32; k += 8) {
        int o = by * 32 + ty + k;
        tile[ty + k][tx] = W[o * IN_F + bx * 32 + tx];
    }
    __syncthreads();
#pragma unroll
    for (int k = 0; k < 32; k += 8) {
        int i = bx * 32 + ty + k;
        Wt[i * OUT_F + by * 32 + tx] = tile[tx][ty + k];
    }
}

// ---------------------------------------------------------------------------
// K_A: C[t,b,o] = sum over active i of Wt[i][o], fp64. One block per (t,b).
// ---------------------------------------------------------------------------
__global__ __launch_bounds__(256) void syn_current(const float* __restrict__ x,
                                                   const float* __restrict__ Wt,
                                                   double* __restrict__ C) {
    const int tb  = blockIdx.x;          // t*B + b
    const int tid = threadIdx.x;

    __shared__ int s_idx[IN_F];
    __shared__ int s_cnt;

    if (tid < 64) {                      // wave 0 builds ascending active list
        const float* xr = x + (size_t)tb * IN_F;
        int base = 0;
#pragma unroll
        for (int j = 0; j < 8; ++j) {
            const float v = xr[j * 64 + tid];
            const unsigned long long m = __ballot(v > 0.5f);
            if (v > 0.5f) {
                const int pos = base + __popcll(m & ((1ull << tid) - 1ull));
                s_idx[pos] = j * 64 + tid;
            }
            base += __popcll(m);
        }
        if (tid == 0) s_cnt = base;
    }
    __syncthreads();

    const int cnt = s_cnt;
    double c0 = 0.0, c1 = 0.0;
    const float* W0 = Wt + tid;
    const float* W1 = Wt + tid + 256;
    for (int k = 0; k < cnt; ++k) {
        const int i = s_idx[k];          // LDS broadcast (uniform address)
        c0 += (double)W0[(size_t)i * OUT_F];
        c1 += (double)W1[(size_t)i * OUT_F];
    }

    double* Cr = C + (size_t)tb * OUT_F;
    Cr[tid]       = c0;
    Cr[tid + 256] = c1;
}

// ---------------------------------------------------------------------------
// K_B: elementwise LIF scan, one thread per (b,o). fp64 recurrence,
// double-buffered 10-step chunks (static indices only).
// ---------------------------------------------------------------------------
#define LIF_STEP(BUF, J, CB)                                                   \
    {                                                                          \
        const int t = (CB) * 10 + (J);                                         \
        I = ALPHA_D * I + BUF[J];                                              \
        U = BETA_D * U + I;                                                    \
        const double Sv = (U >= 1.0) ? 1.0 : 0.0;                              \
        S_out[(size_t)t * N + pos] = (float)Sv;                                \
        Uh[(size_t)(2 * t) * N + pos] = (float)U;                              \
        U -= Sv;                                                               \
        Uh[(size_t)(2 * t + 1) * N + pos] = (float)U;                          \
        U -= Sv;                                                               \
    }

__global__ __launch_bounds__(256) void lif_pointwise(const double* __restrict__ C,
                                                     float* __restrict__ S_out,
                                                     float* __restrict__ Uh) {
    const int pos = blockIdx.x * 256 + threadIdx.x;   // b*OUT + o
    const size_t N = (size_t)B_N * OUT_F;

    double I = 0.0, U = 0.0;
    double bufA[10], bufB[10];

#pragma unroll
    for (int j = 0; j < 10; ++j) bufA[j] = C[(size_t)j * N + pos];

    for (int cb = 0; cb < 10; cb += 2) {
#pragma unroll
        for (int j = 0; j < 10; ++j) bufB[j] = C[((size_t)(cb + 1) * 10 + j) * N + pos];
#pragma unroll
        for (int j = 0; j < 10; ++j) LIF_STEP(bufA, j, cb)
        if (cb + 2 < 10) {
#pragma unroll
            for (int j = 0; j < 10; ++j) bufA[j] = C[((size_t)(cb + 2) * 10 + j) * N + pos];
        }
#pragma unroll
        for (int j = 0; j < 10; ++j) LIF_STEP(bufB, j, cb + 1)
    }
}

// ---------------------------------------------------------------------------
// K3'': MFMA trace. trace[b] = P^T (100 x 512) @ X (100 x 512), batched over b.
// P[t][o] = sigma'(U_post[t,b,o]) * gamma^(99-t)  (bf16; X binary -> exact).
// Per block: one b, 128(o) x 128(i) tile, K padded to 128.
// LDS: Pa[o][k], Xb[i][k] bf16, k-contiguous so A/B fragment loads are single
// ds_read_b128; byte ^= ((row&7)<<4) XOR swizzle (T2/G4) kills the 256B-stride
// same-bank aliasing on both write and read sides.
// Both operands use the same [feat][k] staging => result is invariant to the
// MFMA's internal lane->k permutation; D layout: col=lane&15, row=(l>>4)*4+reg.
// Grid swizzle: all 16 tiles of one b land on one XCD (L2 reuse of Uh/x).
// ---------------------------------------------------------------------------
__global__ __launch_bounds__(256) void trace_mfma(const float* __restrict__ x,
                                                  const float* __restrict__ Uh,
                                                  float* __restrict__ trace) {
    __shared__ unsigned short Pa[128 * 128];   // [o][k] swizzled, 32 KB
    __shared__ unsigned short Xb[128 * 128];   // [i][k] swizzled, 32 KB

    const int idx  = blockIdx.x;
    const int xcd  = idx & 7;
    const int slot = idx >> 3;                 // 0..255
    const int b    = xcd * 16 + (slot >> 4);   // 16 b's per XCD
    const int tile = slot & 15;
    const int ot   = tile >> 2;                // 0..3
    const int it   = tile & 3;                 // 0..3
    const int tid  = threadIdx.x;

    char* const pbase = (char*)Pa;
    char* const xbase = (char*)Xb;

    // ---- stage X tile: Xb[i][k] = x[k][b][it*128+i], zeros for k>=100 ----
#pragma unroll
    for (int r = 0; r < 8; ++r) {
        const int g  = tid + r * 256;          // 2048 groups: i(128) x kg(16)
        const int i  = g & 127;
        const int kg = g >> 7;
        unsigned int h[4];
#pragma unroll
        for (int jj = 0; jj < 4; ++jj) {
            const int t0 = kg * 8 + jj * 2, t1 = t0 + 1;
            float v0 = 0.f, v1 = 0.f;
            if (t0 < T_STEPS) v0 = x[(size_t)t0 * (B_N * IN_F) + b * IN_F + it * 128 + i];
            if (t1 < T_STEPS) v1 = x[(size_t)t1 * (B_N * IN_F) + b * IN_F + it * 128 + i];
            h[jj] = (unsigned int)f2bf(v0) | ((unsigned int)f2bf(v1) << 16);
        }
        unsigned int off = (unsigned int)(i * 256 + kg * 16) ^ ((unsigned int)(i & 7) << 4);
        *(uint4*)(xbase + off) = make_uint4(h[0], h[1], h[2], h[3]);
    }

    // ---- stage P tile: Pa[o][k] = sigma'(U_post[k,b,ot*128+o]) * gamma^(99-k) ----
#pragma unroll
    for (int r = 0; r < 8; ++r) {
        const int g  = tid + r * 256;
        const int o  = g & 127;
        const int kg = g >> 7;
        unsigned int h[4];
#pragma unroll
        for (int jj = 0; jj < 4; ++jj) {
            unsigned int hw[2];
#pragma unroll
            for (int e = 0; e < 2; ++e) {
                const int t = kg * 8 + jj * 2 + e;
                float p = 0.f;
                if (t < T_STEPS) {
                    const float u  = Uh[(size_t)(2 * t + 1) * (B_N * OUT_F) + b * OUT_F + ot * 128 + o];
                    const float du = fabsf(u - 1.0f);
                    const float d  = 1.0f + 0.03f * du;
                    const float gp = __expf(-0.05f * (float)(T_STEPS - 1 - t));
                    p = gp / (d * d);
                }
                hw[e] = f2bf(p);
            }
            h[jj] = hw[0] | (hw[1] << 16);
        }
        unsigned int off = (unsigned int)(o * 256 + kg * 16) ^ ((unsigned int)(o & 7) << 4);
        *(uint4*)(pbase + off) = make_uint4(h[0], h[1], h[2], h[3]);
    }
    __syncthreads();

    // ---- compute: each wave does a 64x64 quadrant ----
    const int w    = tid >> 6;                 // 0..3
    const int l    = tid & 63;
    const int wo   = (w >> 1) * 64;            // o-quadrant base
    const int wi   = (w & 1) * 64;             // i-quadrant base
    const int lo16 = l & 15;
    const int g4   = l >> 4;                   // 0..3

    f32x4 acc[4][4];
#pragma unroll
    for (int m = 0; m < 4; ++m)
#pragma unroll
        for (int n = 0; n < 4; ++n) acc[m][n] = (f32x4){0.f, 0.f, 0.f, 0.f};

#pragma unroll
    for (int kk = 0; kk < 4; ++kk) {           // K = 4 x 32
        bf16x8 af[4], bfr[4];
#pragma unroll
        for (int m = 0; m < 4; ++m) {
            const int row = wo + m * 16 + lo16;
            const unsigned int off = (unsigned int)(row * 256 + kk * 64 + g4 * 16)
                                     ^ ((unsigned int)(row & 7) << 4);
            af[m] = *(const bf16x8*)(pbase + off);
        }
#pragma unroll
        for (int n = 0; n < 4; ++n) {
            const int row = wi + n * 16 + lo16;
            const unsigned int off = (unsigned int)(row * 256 + kk * 64 + g4 * 16)
                                     ^ ((unsigned int)(row & 7) << 4);
            bfr[n] = *(const bf16x8*)(xbase + off);
        }
#pragma unroll
        for (int m = 0; m < 4; ++m)
#pragma unroll
            for (int n = 0; n < 4; ++n)
                acc[m][n] = __builtin_amdgcn_mfma_f32_16x16x32_bf16(af[m], bfr[n], acc[m][n], 0, 0, 0);
    }

    // ---- epilogue: D col = lane&15, row = (lane>>4)*4 + reg ----
    float* tb = trace + (size_t)b * (OUT_F * IN_F);
#pragma unroll
    for (int m = 0; m < 4; ++m) {
#pragma unroll
        for (int rr = 0; rr < 4; ++rr) {
            const int o = ot * 128 + wo + m * 16 + g4 * 4 + rr;
#pragma unroll
            for (int n = 0; n < 4; ++n) {
                const int i = it * 128 + wi + n * 16 + lo16;
                tb[(size_t)o * IN_F + i] = acc[m][n][rr];
            }
        }
    }
}

// ---------------------------------------------------------------------------
extern "C" void kernel_launch(void* const* d_in, const int* in_sizes, int n_in,
                              void* d_out, int out_size, void* d_ws, size_t ws_size,
                              hipStream_t stream) {
    const float* x = (const float*)d_in[0];   // (T, B, IN) binary spikes
    const float* W = (const float*)d_in[1];   // (OUT, IN)

    float* out   = (float*)d_out;
    float* S_out = out;                                            // (T, B, OUT)
    float* Uh    = out + (size_t)T_STEPS * B_N * OUT_F;            // (2T, B, OUT)
    float* trace = Uh + (size_t)2 * T_STEPS * B_N * OUT_F;         // (B, OUT, IN)

    float* Wt = (float*)d_ws;                                      // (IN, OUT), 1 MiB

    // Scratch for C: reuse the trace region of d_out (134 MB >= 52 MB needed);
    // trace_mfma runs last and overwrites it.
    double* C = (double*)trace;

    transposeW<<<256, 256, 0, stream>>>(W, Wt);
    syn_current<<<T_STEPS * B_N, 256, 0, stream>>>(x, Wt, C);
    lif_pointwise<<<B_N * OUT_F / 256, 256, 0, stream>>>(C, S_out, Uh);
    trace_mfma<<<16 * B_N, 256, 0, stream>>>(x, Uh, trace);
}